// Round 1
// 547.064 us; speedup vs baseline: 1.0283x; 1.0283x over previous
//
#include <hip/hip_runtime.h>
#include <math.h>

typedef __attribute__((ext_vector_type(8))) short bf16x8;
typedef __attribute__((ext_vector_type(4))) float f32x4;
typedef __attribute__((ext_vector_type(4))) unsigned short u16x4;

__device__ inline unsigned short f2bf(float f) {
    union { float f; unsigned u; } v; v.f = f;
    unsigned r = v.u + 0x7FFFu + ((v.u >> 16) & 1u);   // RNE
    return (unsigned short)(r >> 16);
}
__device__ inline float bf2f(unsigned short h) {
    union { unsigned u; float f; } v; v.u = ((unsigned)h) << 16;
    return v.f;
}

// async 16B global -> LDS. LDS dest is wave-uniform base + lane*16 (m104).
__device__ inline void load_lds16(const void* g, void* l) {
    __builtin_amdgcn_global_load_lds(
        (const __attribute__((address_space(1))) unsigned int*)g,
        (__attribute__((address_space(3))) unsigned int*)l,
        16, 0, 0);
}

// One-launch f32->bf16 convert of 4 segments (seg 3 zero-padded nDs..nDd).
// All segment sizes are multiples of 4.
__global__ __launch_bounds__(256) void convert_all(
    const float* __restrict__ sA, unsigned short* __restrict__ dA, long nA,
    const float* __restrict__ sB, unsigned short* __restrict__ dB, long nB,
    const float* __restrict__ sC, unsigned short* __restrict__ dC, long nC,
    const float* __restrict__ sD, unsigned short* __restrict__ dD, long nDs, long nDd)
{
    long i = ((long)blockIdx.x * 256 + threadIdx.x) * 4;
    const float* s; unsigned short* d; long nsrc;
    if (i < nA)              { s = sA + i; d = dA + i; nsrc = nA - i; }
    else if ((i -= nA) < nB) { s = sB + i; d = dB + i; nsrc = nB - i; }
    else if ((i -= nB) < nC) { s = sC + i; d = dC + i; nsrc = nC - i; }
    else if ((i -= nC) < nDd){ s = sD + i; d = dD + i; nsrc = nDs - i; }
    else return;
    float4 v = make_float4(0.f, 0.f, 0.f, 0.f);
    if (nsrc >= 4) v = *(const float4*)s;
    u16x4 o;
    o[0] = f2bf(v.x); o[1] = f2bf(v.y); o[2] = f2bf(v.z); o[3] = f2bf(v.w);
    *(u16x4*)d = o;
}

// Tiled MFMA GEMM, both inputs bf16, global_load_lds width-16 staging (m97 recipe).
// out[m,n] = epilogue( sum_k A[m,k]*B[n,k] + bias[n] )
// 128x128 tile, BK=64, 256 threads = 4 waves in 2x2, wave = 4x4 of 16x16x32 MFMA.
// OPERAND-SWAPPED MFMA: acc = mfma(bfv, af, acc). C/D layout col=lane&15,
// row=quad*4+reg (m89/m91) then maps row->n, col->m, so each thread holds 4
// CONSECUTIVE n per fragment -> vectorized f32x4 / u16x4 epilogue stores
// (16 store instrs/thread instead of 64). Critical at K=512 (only 8 K-iters,
// epilogue poorly amortized).
// LDS layout: row-major 128x64 bf16, per-row XOR swizzle: LDS[row][p] holds global
// chunk p^(row&7) (chunks of 8 elems) -> fragment ds_read_b128 lands 2-way max
// (free, m136).
// MODE 2: f32x4 store v/1.5 for n<Nreal (ld=Nreal; Nreal%4==0 so 4-aligned
//         fragments are all-in or all-out)
// MODE 3: n<nsplit -> bf16 u16x4 store (ld=nsplit, bias0); else f32x4
//         softplus(v)+1e-3 (ld=Npad-nsplit, bias1)
// SWZ: XCD-locality swizzle (requires (M/128)%8==0).
template <int MODE, bool SWZ>
__global__ __launch_bounds__(256) void gemm_bf16(
    const unsigned short* __restrict__ A, const unsigned short* __restrict__ Bm,
    const float* __restrict__ bias0, const float* __restrict__ bias1,
    void* __restrict__ out0v, void* __restrict__ out1v,
    int M, int Npad, int Nreal, int K, int nsplit)
{
    __shared__ __align__(16) unsigned short As[128 * 64];
    __shared__ __align__(16) unsigned short Bs[128 * 64];

    const int tid  = threadIdx.x;
    const int nblk = Npad >> 7;
    int mt, nt;
    if constexpr (SWZ) {
        const int per = (M >> 7) >> 3;      // m-tiles per XCD
        const int x = blockIdx.x & 7;
        const int j = blockIdx.x >> 3;
        const int jm = j / nblk;
        mt = x * per + jm;
        nt = j - jm * nblk;
    } else {
        mt = blockIdx.x / nblk;
        nt = blockIdx.x - mt * nblk;
    }
    const int m0 = mt << 7;
    const int n0 = nt << 7;

    const int lane = tid & 63;
    const int wid  = tid >> 6;
    const int wm   = (wid & 1) << 6;
    const int wn   = (wid >> 1) << 6;
    const int quad = lane >> 4;
    const int l15  = lane & 15;
    const int l7   = l15 & 7;

    // staging geometry: wave w stages rows w*32..w*32+31 of both tiles,
    // 4 issues of 8 rows (64 lanes x 16B = 1024B = 8 rows of 128B).
    const int lrow = lane >> 3;                   // 0..7 within 8-row group
    const int lcol = ((lane & 7) ^ lrow) << 3;    // swizzled global col (elems)

    const unsigned short* Ab = A  + (size_t)(m0 + wid * 32 + lrow) * K + lcol;
    const unsigned short* Bb = Bm + (size_t)(n0 + wid * 32 + lrow) * K + lcol;
    unsigned short* AsW = &As[(wid * 32) * 64];
    unsigned short* BsW = &Bs[(wid * 32) * 64];

    f32x4 acc[4][4];
    #pragma unroll
    for (int i = 0; i < 4; ++i)
        #pragma unroll
        for (int j = 0; j < 4; ++j)
            acc[i][j] = f32x4{0.f, 0.f, 0.f, 0.f};

    for (int kt = 0; kt < K; kt += 64) {
        __syncthreads();   // previous iteration's LDS reads complete
        #pragma unroll
        for (int i = 0; i < 4; ++i) {
            load_lds16(Ab + (size_t)(i * 8) * K + kt, AsW + i * 8 * 64);
            load_lds16(Bb + (size_t)(i * 8) * K + kt, BsW + i * 8 * 64);
        }
        __syncthreads();   // compiler drains vmcnt before s_barrier (m97)

        #pragma unroll
        for (int kk = 0; kk < 64; kk += 32) {
            const int kq = kk >> 3;   // chunk base: 0 or 4
            bf16x8 af[4], bfv[4];
            #pragma unroll
            for (int mi = 0; mi < 4; ++mi)
                af[mi] = *(const bf16x8*)&As[(wm + mi * 16 + l15) * 64
                                             + (((kq + quad) ^ l7) << 3)];
            #pragma unroll
            for (int ni = 0; ni < 4; ++ni)
                bfv[ni] = *(const bf16x8*)&Bs[(wn + ni * 16 + l15) * 64
                                              + (((kq + quad) ^ l7) << 3)];
            // swapped operands: D[row=n (quad*4+reg), col=m (l15)]
            #pragma unroll
            for (int mi = 0; mi < 4; ++mi)
                #pragma unroll
                for (int ni = 0; ni < 4; ++ni)
                    acc[mi][ni] = __builtin_amdgcn_mfma_f32_16x16x32_bf16(
                        bfv[ni], af[mi], acc[mi][ni], 0, 0, 0);
        }
    }

    // epilogue (swapped layout): thread owns m = ...+l15 (one row per fragment),
    // n = ...+quad*4+reg (4 consecutive cols) -> vector stores.
    if constexpr (MODE == 2) {
        float* o = (float*)out0v;
        #pragma unroll
        for (int ni = 0; ni < 4; ++ni) {
            const int nb = n0 + wn + ni * 16 + (quad << 2);
            if (nb >= Nreal) continue;          // Nreal%4==0: all-or-nothing
            const float4 bv = *(const float4*)&bias0[nb];
            #pragma unroll
            for (int mi = 0; mi < 4; ++mi) {
                const int m = m0 + wm + mi * 16 + l15;
                f32x4 v;
                v[0] = (acc[mi][ni][0] + bv.x) * (1.0f / 1.5f);
                v[1] = (acc[mi][ni][1] + bv.y) * (1.0f / 1.5f);
                v[2] = (acc[mi][ni][2] + bv.z) * (1.0f / 1.5f);
                v[3] = (acc[mi][ni][3] + bv.w) * (1.0f / 1.5f);
                *(f32x4*)&o[(size_t)m * Nreal + nb] = v;
            }
        }
    } else {  // MODE 3
        if (n0 < nsplit) {
            unsigned short* o = (unsigned short*)out0v;
            #pragma unroll
            for (int ni = 0; ni < 4; ++ni) {
                const int nb = n0 + wn + ni * 16 + (quad << 2);
                const float4 bv = *(const float4*)&bias0[nb];
                #pragma unroll
                for (int mi = 0; mi < 4; ++mi) {
                    const int m = m0 + wm + mi * 16 + l15;
                    u16x4 ov;
                    ov[0] = f2bf(acc[mi][ni][0] + bv.x);
                    ov[1] = f2bf(acc[mi][ni][1] + bv.y);
                    ov[2] = f2bf(acc[mi][ni][2] + bv.z);
                    ov[3] = f2bf(acc[mi][ni][3] + bv.w);
                    *(u16x4*)&o[(size_t)m * nsplit + nb] = ov;
                }
            }
        } else {
            float* o = (float*)out1v;
            const int ld1 = Npad - nsplit;
            #pragma unroll
            for (int ni = 0; ni < 4; ++ni) {
                const int nb = n0 + wn + ni * 16 + (quad << 2) - nsplit;
                const float4 bv = *(const float4*)&bias1[nb];
                #pragma unroll
                for (int mi = 0; mi < 4; ++mi) {
                    const int m = m0 + wm + mi * 16 + l15;
                    f32x4 v;
                    #pragma unroll
                    for (int r = 0; r < 4; ++r) {
                        float x = acc[mi][ni][r] + ((const float*)&bv)[r];
                        float sp = (x > 20.f) ? x : log1pf(expf(x));
                        v[r] = sp + 1e-3f;
                    }
                    *(f32x4*)&o[(size_t)m * ld1 + nb] = v;
                }
            }
        }
    }
}

// pre[b,s,d] = f[b,d] + sum_r L[b,d,r]*z[b,s,r] + diag[b,d]*nd[b,s,d], stored bf16.
// One b per block; 256 threads = 2 s-halves x 128 threads; each thread owns 4
// consecutive d. Grid = B (1024 blocks -> 4 blocks/CU vs 2 before), s-loop
// unrolled x2 for memory-level parallelism.
__global__ __launch_bounds__(256) void sample_kernel(
    const float* __restrict__ features, const unsigned short* __restrict__ lr_cov,
    const float* __restrict__ diag, const float* __restrict__ nz_lr,
    const float* __restrict__ nz_diag, unsigned short* __restrict__ pre,
    int S, int D)
{
    const int tid = threadIdx.x;
    const int b   = blockIdx.x;
    const int sh  = tid >> 7;                 // s-half 0/1
    const int t   = tid & 127;
    const int d0  = t << 2;

    __shared__ __align__(16) float snz[64 * 16];
    // 64*16 = 1024 floats = 256 float4: one per thread
    ((float4*)snz)[tid] = ((const float4*)(nz_lr + (size_t)b * S * 16))[tid];

    float4 f  = *(const float4*)(features + (size_t)b * D + d0);
    float4 dg = *(const float4*)(diag + (size_t)b * D + d0);
    float L[4][16];
    const unsigned short* lp = lr_cov + (size_t)b * D * 16 + (size_t)d0 * 16;
    #pragma unroll
    for (int j = 0; j < 4; ++j) {
        bf16x8 a = *(const bf16x8*)(lp + j * 16);
        bf16x8 c = *(const bf16x8*)(lp + j * 16 + 8);
        #pragma unroll
        for (int r = 0; r < 8; ++r) {
            L[j][r]     = bf2f((unsigned short)a[r]);
            L[j][8 + r] = bf2f((unsigned short)c[r]);
        }
    }
    __syncthreads();

    const int s0 = sh * (S >> 1);
    const float* ndp = nz_diag + (size_t)b * S * D + (size_t)s0 * D + d0;
    unsigned short* pp = pre + (size_t)b * S * D + (size_t)s0 * D + d0;
    const int SH = S >> 1;
    for (int s = 0; s < SH; s += 2) {
        float4 nd0 = *(const float4*)(ndp + (size_t)s * D);
        float4 nd1 = *(const float4*)(ndp + (size_t)(s + 1) * D);
        float a0 = f.x + dg.x * nd0.x, a1 = f.y + dg.y * nd0.y;
        float a2 = f.z + dg.z * nd0.z, a3 = f.w + dg.w * nd0.w;
        float b0 = f.x + dg.x * nd1.x, b1 = f.y + dg.y * nd1.y;
        float b2 = f.z + dg.z * nd1.z, b3 = f.w + dg.w * nd1.w;
        const float* z0 = &snz[(s0 + s) * 16];
        const float* z1 = &snz[(s0 + s + 1) * 16];
        #pragma unroll
        for (int r = 0; r < 16; ++r) {
            float zv0 = z0[r], zv1 = z1[r];
            a0 += L[0][r] * zv0; a1 += L[1][r] * zv0;
            a2 += L[2][r] * zv0; a3 += L[3][r] * zv0;
            b0 += L[0][r] * zv1; b1 += L[1][r] * zv1;
            b2 += L[2][r] * zv1; b3 += L[3][r] * zv1;
        }
        u16x4 o0, o1;
        o0[0] = f2bf(a0); o0[1] = f2bf(a1); o0[2] = f2bf(a2); o0[3] = f2bf(a3);
        o1[0] = f2bf(b0); o1[1] = f2bf(b1); o1[2] = f2bf(b2); o1[3] = f2bf(b3);
        *(u16x4*)(pp + (size_t)s * D) = o0;
        *(u16x4*)(pp + (size_t)(s + 1) * D) = o1;
    }
}

extern "C" void kernel_launch(void* const* d_in, const int* in_sizes, int n_in,
                              void* d_out, int out_size, void* d_ws, size_t ws_size,
                              hipStream_t stream)
{
    const float* features = (const float*)d_in[0];
    const float* W_cov    = (const float*)d_in[1];
    const float* b_cov    = (const float*)d_in[2];
    const float* W_diag   = (const float*)d_in[3];
    const float* b_diag   = (const float*)d_in[4];
    const float* W_cls    = (const float*)d_in[5];
    const float* b_cls    = (const float*)d_in[6];
    const float* nz_diag  = (const float*)d_in[7];
    const float* nz_lr    = (const float*)d_in[8];

    const int D    = in_sizes[4];            // 512
    const int DR   = in_sizes[2];            // 8192
    const int B    = in_sizes[0] / D;        // 1024
    const int S    = in_sizes[7] / (B * D);  // 64
    const int C    = in_sizes[6];            // 1000
    const int M    = B * S;                  // 65536
    const int Cpad = (C + 127) & ~127;       // 1024
    const int Ncat = DR + D;                 // 8704

    // ws layout (pre overlays dead featb+wcat region): ~87 MB total
    char* ws = (char*)d_ws;
    unsigned short* lrcov = (unsigned short*)ws;                      // B*DR bf16
    float*          diag  = (float*)(ws + (size_t)B * DR * 2);        // B*D f32
    unsigned short* wclsb = (unsigned short*)((char*)diag + (size_t)B * D * 4); // Cpad*D
    char* X = (char*)wclsb + (size_t)Cpad * D * 2;
    unsigned short* featb = (unsigned short*)X;                       // B*D (dead after gemm1)
    unsigned short* wcatb = featb + (size_t)B * D;                    // Ncat*D (dead after gemm1)
    unsigned short* pre   = (unsigned short*)X;                       // M*D (overlays featb+wcatb)

    // 1) all f32 -> bf16 converts in one launch
    {
        long n1 = (long)DR * D;    // W_cov -> wcatb[0:n1]
        long n2 = (long)D * D;     // W_diag -> wcatb[n1:]
        long n3 = (long)B * D;     // features -> featb
        long n4s = (long)C * D, n4d = (long)Cpad * D;  // W_cls -> wclsb (zero-padded)
        long total = n1 + n2 + n3 + n4d;
        convert_all<<<dim3((unsigned)(total / 1024)), 256, 0, stream>>>(
            W_cov, wcatb, n1,
            W_diag, wcatb + n1, n2,
            features, featb, n3,
            W_cls, wclsb, n4s, n4d);
    }

    // 2) fused: lr_cov (bf16) + diag (softplus f32) in one GEMM over [W_cov; W_diag]
    gemm_bf16<3, false><<<dim3((B / 128) * (Ncat / 128)), 256, 0, stream>>>(
        featb, wcatb, b_cov, b_diag, lrcov, diag, B, Ncat, Ncat, D, DR);

    // 3) pre_logits (bf16)
    sample_kernel<<<dim3(B), 256, 0, stream>>>(
        features, lrcov, diag, nz_lr, nz_diag, pre, S, D);

    // 4) logits = (pre @ W_cls^T + b_cls) / 1.5, XCD-swizzled for A-tile L2 reuse
    gemm_bf16<2, true><<<dim3((M / 128) * (Cpad / 128)), 256, 0, stream>>>(
        pre, wclsb, b_cls, nullptr, d_out, nullptr, M, Cpad, C, D, DR);
}